// Round 7
// baseline (289.836 us; speedup 1.0000x reference)
//
#include <hip/hip_runtime.h>

// RNN_arch_2: 16-step vanilla RNN, B=16384, D_IN=64, D_H=256, D_MID=64, D_OUT=4.
// R9: design for the allocator we HAVE, not the one we want. Six builds show
// hipcc never keeps persistent weight arrays in registers (alloc 128,128,128,
// 128,64 vs demand up to 270) - it remats global f32 loads + f16 cvt at every
// use, every step (~900 KB/step/CU of L2 requests + cvt VALU = the 128-153us
// floor). So: make the per-use operand stream cheap instead of fighting it.
//  - prep kernel converts Wi/Wh/Wo to f16 in d_ws ONCE. A-fragments then come
//    from global f16 as plain 16B dwordx4 loads: no cvt VALU, half the bytes,
//    L2-resident (196 KB << 4 MB/XCD).
//  - 1 block/CU x 512 thr, BLK_ROWS=64, grid=256 (LDS ~88KB caps 1 blk/CU):
//    per-CU A-traffic = 224 KB/step ~= 3.7K cyc @ ~60 B/cyc L2; MFMA/LDS/VALU
//    hide under it. Expect ~25-40us.
//  - opaque_ptr (SGPR pass-through asm) re-roots weight pointers every step:
//    blocks LICM from hoisting 28 invariant loads into registers (which the
//    allocator would then spill - the R5 disaster).
//  - rule-20 fix: mid's h-fragment pick via wave-uniform ternary (cndmask),
//    not runtime array index (R5/R8 had hf[mth+j] -> scratch risk).
// Skeleton (R5/R8-verified): h double-buffered f16 in LDS, ONE barrier/step,
// fused phase (pre for h_{t+1} + h2o(h_t) share h fragments), W as A-operand
// (C row = weight-dim -> ds_write_b64 epilogues), fc lagged 2 steps.

typedef _Float16 half8 __attribute__((ext_vector_type(8)));
typedef _Float16 half4 __attribute__((ext_vector_type(4)));
typedef float floatx4 __attribute__((ext_vector_type(4)));

#define T_STEPS  16
#define BATCH    16384
#define BLK_ROWS 64
#define HS       264   // h_lds row stride (f16): 528B -> 2-way bank alias, free
#define MS       72    // mid_lds row stride (f16)
// d_ws layout (f16 element offsets): Wi[256x64], Wh[256x256], Wo[64x256]
#define WS_WI 0
#define WS_WH 16384
#define WS_WO 81920    // total 98304 f16 = 192 KB

__device__ inline float fast_tanh(float x) {
    // tanh(x) = 1 - 2/(1+exp2(2*log2e*x)); saturates correctly at +-inf
    float t = __builtin_amdgcn_exp2f(x * 2.8853900817779268f);
    return 1.0f - 2.0f * __builtin_amdgcn_rcpf(t + 1.0f);
}

__device__ inline half8 pack8(float4 a, float4 b) {
    half8 h;
    h[0] = (_Float16)a.x; h[1] = (_Float16)a.y; h[2] = (_Float16)a.z; h[3] = (_Float16)a.w;
    h[4] = (_Float16)b.x; h[5] = (_Float16)b.y; h[6] = (_Float16)b.z; h[7] = (_Float16)b.w;
    return h;
}

__device__ inline half8 cvt8(const float* __restrict__ p) {
    return pack8(((const float4*)p)[0], ((const float4*)p)[1]);
}

// Re-root a pointer through an opaque SGPR asm: loads derived from it cannot
// be hoisted/CSE'd across iterations (blocks LICM re-creating register arrays).
__device__ __forceinline__ const _Float16* opaque_ptr(const _Float16* p) {
    asm volatile("" : "+s"(p));
    return p;
}

// ---- prep: weights f32 -> f16 into d_ws (one-time, L2-resident afterwards)
__global__ __launch_bounds__(256) void cvt_w(
    const float* __restrict__ Wi, const float* __restrict__ Wh,
    const float* __restrict__ Wo, _Float16* __restrict__ ws)
{
    const int i = blockIdx.x * 256 + threadIdx.x;   // grid 256 -> i < 65536
    if (i < 16384) ws[WS_WI + i] = (_Float16)Wi[i];
    ws[WS_WH + i] = (_Float16)Wh[i];
    if (i < 16384) ws[WS_WO + i] = (_Float16)Wo[i];
}

// Fused MFMA phase. mfma(a=W[idx][k], b=act[batch][k]) gives
// C[row = weight-dim (quad*4+r)][col = batch (l16)].
// Wave w: pre n-strip = cols [w*32, w*32+32), all 4 m-tiles;
//         mid: n-tile (w>>1), m-tiles {modd*2, modd*2+1} (modd = w&1).
template<int DO_PRE, int DO_MID>
__device__ __forceinline__ void mfma_phase(
    const _Float16* __restrict__ hcur,
    const _Float16* __restrict__ wi16, const _Float16* __restrict__ wh16,
    const _Float16* __restrict__ wo16, const float* __restrict__ xb,
    floatx4 (&acc)[4][2], floatx4 (&ac2)[2],
    int w, int l16, int quad, int modd)
{
    const int jn0 = w * 32 + l16;          // pre weight row, nt=0
    // h-part (K slices 2..9 of pre) + h2o share the same h fragments
    #pragma unroll
    for (int ks2 = 0; ks2 < 8; ++ks2) {
        half8 hf[4];
        #pragma unroll
        for (int mt = 0; mt < 4; ++mt)
            hf[mt] = *(const half8*)&hcur[(mt * 16 + l16) * HS + ks2 * 32 + quad * 8];
        if (DO_MID) {
            half8 wofr = *(const half8*)&wo16[(size_t)((w >> 1) * 16 + l16) * 256
                                              + ks2 * 32 + quad * 8];
            half8 m0 = modd ? hf[2] : hf[0];   // wave-uniform cndmask select
            half8 m1 = modd ? hf[3] : hf[1];   // (NOT runtime array index)
            ac2[0] = __builtin_amdgcn_mfma_f32_16x16x32_f16(wofr, m0, ac2[0], 0, 0, 0);
            ac2[1] = __builtin_amdgcn_mfma_f32_16x16x32_f16(wofr, m1, ac2[1], 0, 0, 0);
        }
        if (DO_PRE) {
            #pragma unroll
            for (int nt = 0; nt < 2; ++nt) {
                half8 wa = *(const half8*)&wh16[(size_t)(jn0 + nt * 16) * 256
                                                + ks2 * 32 + quad * 8];
                #pragma unroll
                for (int mt = 0; mt < 4; ++mt)
                    acc[mt][nt] = __builtin_amdgcn_mfma_f32_16x16x32_f16(
                        wa, hf[mt], acc[mt][nt], 0, 0, 0);
            }
        }
    }
    // x-part (K slices 0..1): x B-frags cvt'd at point of use
    if (DO_PRE) {
        #pragma unroll
        for (int k2 = 0; k2 < 2; ++k2) {
            half8 wa[2];
            #pragma unroll
            for (int nt = 0; nt < 2; ++nt)
                wa[nt] = *(const half8*)&wi16[(size_t)(jn0 + nt * 16) * 64
                                              + k2 * 32 + quad * 8];
            #pragma unroll
            for (int mt = 0; mt < 4; ++mt) {
                half8 a = cvt8(xb + (size_t)(mt * 16 + l16) * 64 + k2 * 32 + quad * 8);
                #pragma unroll
                for (int nt = 0; nt < 2; ++nt)
                    acc[mt][nt] = __builtin_amdgcn_mfma_f32_16x16x32_f16(
                        wa[nt], a, acc[mt][nt], 0, 0, 0);
            }
        }
    }
}

// h = tanh(pre + bias) -> h_lds[nxt]; C row = hidden-dim -> 4 consecutive f16
__device__ __forceinline__ void epi_h(_Float16* __restrict__ hnxt,
                                      const floatx4 (&acc)[4][2],
                                      const float* __restrict__ biasPre,
                                      int w, int l16, int quad)
{
    #pragma unroll
    for (int nt = 0; nt < 2; ++nt) {
        int hb = w * 32 + nt * 16 + quad * 4;
        float4 bias = *(const float4*)&biasPre[hb];
        #pragma unroll
        for (int mt = 0; mt < 4; ++mt) {
            int mb = mt * 16 + l16;
            half4 v;
            v[0] = (_Float16)fast_tanh(acc[mt][nt][0] + bias.x);
            v[1] = (_Float16)fast_tanh(acc[mt][nt][1] + bias.y);
            v[2] = (_Float16)fast_tanh(acc[mt][nt][2] + bias.z);
            v[3] = (_Float16)fast_tanh(acc[mt][nt][3] + bias.w);
            *(half4*)&hnxt[mb * HS + hb] = v;
        }
    }
}

__device__ __forceinline__ void epi_mid(_Float16* __restrict__ midp,
                                        const floatx4 (&ac2)[2],
                                        const float* __restrict__ bo_lds,
                                        int w, int l16, int quad, int modd)
{
    int md = (w >> 1) * 16 + quad * 4;
    float4 bo4 = *(const float4*)&bo_lds[md];
    #pragma unroll
    for (int j = 0; j < 2; ++j) {
        int mb = (modd * 2 + j) * 16 + l16;
        half4 v;
        v[0] = (_Float16)fast_tanh(ac2[j][0] + bo4.x);
        v[1] = (_Float16)fast_tanh(ac2[j][1] + bo4.y);
        v[2] = (_Float16)fast_tanh(ac2[j][2] + bo4.z);
        v[3] = (_Float16)fast_tanh(ac2[j][3] + bo4.w);
        *(half4*)&midp[mb * MS + md] = v;
    }
}

// out = mid @ Wfc^T + bfc : 512 threads = 64 rows x 4 oc x 2 split-K halves
__device__ __forceinline__ void fc_out(const _Float16* __restrict__ midp,
                                       const _Float16* __restrict__ wfc,
                                       const float* __restrict__ bfc,
                                       float* __restrict__ outp,
                                       int ti, int b0, int tid)
{
    const int row = tid >> 3, oc = (tid >> 1) & 3, kh = tid & 1;
    float s = 0.f;
    #pragma unroll
    for (int k8 = 0; k8 < 32; k8 += 8) {
        half8 mv = *(const half8*)&midp[row * MS + kh * 32 + k8];
        half8 wv = *(const half8*)&wfc[oc * 64 + kh * 32 + k8];
        #pragma unroll
        for (int j = 0; j < 8; ++j) s += (float)mv[j] * (float)wv[j];
    }
    s += __shfl_xor(s, 1, 64);
    if (kh == 0)
        outp[((size_t)ti * BATCH + b0 + row) * 4 + oc] = s + bfc[oc];
}

__global__ __launch_bounds__(512) void rnn_kernel(
    const float* __restrict__ x,   const float* __restrict__ hc1,
    const _Float16* __restrict__ ws,
    const float* __restrict__ bi,  const float* __restrict__ bh,
    const float* __restrict__ bo,  const float* __restrict__ Wf,
    const float* __restrict__ bf,  float* __restrict__ out)
{
    __shared__ _Float16 h_lds[2][BLK_ROWS * HS];    // 67.6 KB dbuf h (f16)
    __shared__ _Float16 mid_lds[2][BLK_ROWS * MS];  // 18.4 KB dbuf mid
    __shared__ float    biasPre[256];               // b_i2h + b_h2h
    __shared__ float    bo_lds[64];
    __shared__ _Float16 wfc_lds[4 * 64];
    __shared__ float    bfc_lds[4];
    // ~88 KB -> 1 block/CU by LDS; no persistent register state anywhere.

    const int tid  = threadIdx.x;
    const int w    = tid >> 6;        // wave 0..7
    const int lane = tid & 63;
    const int l16  = lane & 15;
    const int quad = lane >> 4;
    const int modd = w & 1;           // mid m-pair for this wave
    const int b0   = blockIdx.x * BLK_ROWS;

#define ZERO_ACC() do {                                                            \
        _Pragma("unroll")                                                          \
        for (int j = 0; j < 2; ++j) ac2[j] = (floatx4){0.f, 0.f, 0.f, 0.f};        \
        _Pragma("unroll")                                                          \
        for (int mt = 0; mt < 4; ++mt)                                             \
            _Pragma("unroll")                                                      \
            for (int nt = 0; nt < 2; ++nt) acc[mt][nt] = (floatx4){0.f,0.f,0.f,0.f};\
    } while (0)

    // --- one-time LDS init ---
    if (tid < 256) biasPre[tid] = bi[tid] + bh[tid];
    if (tid < 64)  bo_lds[tid] = bo[tid];
    if (tid < 256) wfc_lds[tid] = (_Float16)Wf[tid];
    if (tid < 4)   bfc_lds[tid] = bf[tid];

    // stage hc1 -> h_lds[0]: 64 rows x 256 cols, 8 threads/row
    {
        const int r = tid >> 3, c0 = (tid & 7) * 32;
        const float4* src = (const float4*)&hc1[(size_t)(b0 + r) * 256 + c0];
        #pragma unroll
        for (int i2 = 0; i2 < 8; ++i2) {
            float4 v = src[i2];
            half4 hv;
            hv[0] = (_Float16)v.x; hv[1] = (_Float16)v.y;
            hv[2] = (_Float16)v.z; hv[3] = (_Float16)v.w;
            *(half4*)&h_lds[0][r * HS + c0 + i2 * 4] = hv;
        }
    }

    __syncthreads();

    // ---- i = 0 : pre only ----
    {
        const _Float16* wi16 = opaque_ptr(ws + WS_WI);
        const _Float16* wh16 = opaque_ptr(ws + WS_WH);
        const _Float16* wo16 = opaque_ptr(ws + WS_WO);
        floatx4 acc[4][2], ac2[2];
        ZERO_ACC();
        mfma_phase<1, 0>(h_lds[0], wi16, wh16, wo16, x + (size_t)b0 * 64,
                         acc, ac2, w, l16, quad, modd);
        epi_h(h_lds[1], acc, biasPre, w, l16, quad);
        __syncthreads();
    }

    // ---- main loop: i = 1..15, ONE barrier each ----
    #pragma unroll 1
    for (int i = 1; i <= 15; ++i) {
        const int cur = i & 1, nxt = cur ^ 1;
        // re-rooted each iteration: blocks LICM of the weight loads
        const _Float16* wi16 = opaque_ptr(ws + WS_WI);
        const _Float16* wh16 = opaque_ptr(ws + WS_WH);
        const _Float16* wo16 = opaque_ptr(ws + WS_WO);
        if (i >= 2) fc_out(mid_lds[nxt], wfc_lds, bfc_lds, out, i - 2, b0, tid);
        floatx4 acc[4][2], ac2[2];
        ZERO_ACC();
        mfma_phase<1, 1>(h_lds[cur], wi16, wh16, wo16,
                         x + ((size_t)i * BATCH + b0) * 64,
                         acc, ac2, w, l16, quad, modd);
        epi_h(h_lds[nxt], acc, biasPre, w, l16, quad);
        epi_mid(mid_lds[cur], ac2, bo_lds, w, l16, quad, modd);
        __syncthreads();
    }

    // ---- i = 16 : h2o(h_16) + drain fc ----
    {
        const _Float16* wi16 = opaque_ptr(ws + WS_WI);
        const _Float16* wh16 = opaque_ptr(ws + WS_WH);
        const _Float16* wo16 = opaque_ptr(ws + WS_WO);
        fc_out(mid_lds[1], wfc_lds, bfc_lds, out, 14, b0, tid);
        floatx4 acc[4][2], ac2[2];
        ZERO_ACC();
        mfma_phase<0, 1>(h_lds[0], wi16, wh16, wo16, x,
                         acc, ac2, w, l16, quad, modd);
        epi_mid(mid_lds[0], ac2, bo_lds, w, l16, quad, modd);
        __syncthreads();
        fc_out(mid_lds[0], wfc_lds, bfc_lds, out, 15, b0, tid);
    }

    // ---- h_final (fp32) at offset T*B*4, from h_lds[0] (= h_16) ----
    {
        const int r = tid >> 3, c0 = (tid & 7) * 32;
        float4* dst = (float4*)&out[(size_t)T_STEPS * BATCH * 4 + (size_t)(b0 + r) * 256 + c0];
        #pragma unroll
        for (int i2 = 0; i2 < 8; ++i2) {
            int c = c0 + i2 * 4;
            float4 v;
            v.x = (float)h_lds[0][r * HS + c + 0];
            v.y = (float)h_lds[0][r * HS + c + 1];
            v.z = (float)h_lds[0][r * HS + c + 2];
            v.w = (float)h_lds[0][r * HS + c + 3];
            dst[i2] = v;
        }
    }
#undef ZERO_ACC
}

extern "C" void kernel_launch(void* const* d_in, const int* in_sizes, int n_in,
                              void* d_out, int out_size, void* d_ws, size_t ws_size,
                              hipStream_t stream) {
    const float* x   = (const float*)d_in[0];
    const float* hc1 = (const float*)d_in[1];
    const float* Wi  = (const float*)d_in[2];
    const float* bi  = (const float*)d_in[3];
    const float* Wh  = (const float*)d_in[4];
    const float* bh  = (const float*)d_in[5];
    const float* Wo  = (const float*)d_in[6];
    const float* bo  = (const float*)d_in[7];
    const float* Wf  = (const float*)d_in[8];
    const float* bf  = (const float*)d_in[9];
    _Float16* ws = (_Float16*)d_ws;   // needs 192 KB

    cvt_w<<<256, 256, 0, stream>>>(Wi, Wh, Wo, ws);
    rnn_kernel<<<BATCH / BLK_ROWS, 512, 0, stream>>>(
        x, hc1, ws, bi, bh, bo, Wf, bf, (float*)d_out);
}